// Round 10
// baseline (430.161 us; speedup 1.0000x reference)
//
#include <hip/hip_runtime.h>
#include <hip/hip_bf16.h>
#include <cstdint>
#include <cstddef>

#define NN   50000
#define NE   400000
#define DIN  128
#define DH   512
#define NCLS 128

#define NSCB ((NN + 255) / 256)   // scan blocks = 196

#define NEG_INF (-__builtin_inff())

typedef short short8_t __attribute__((ext_vector_type(8)));
typedef float f32x4   __attribute__((ext_vector_type(4)));

typedef const __attribute__((address_space(1))) void* gas_t;
typedef __attribute__((address_space(3))) void* las_t;

// DMA 16B/lane: LDS dest = wave-uniform base + lane*16 (linear); global src per-lane.
static __device__ inline void load_lds16(const void* g, void* l) {
  __builtin_amdgcn_global_load_lds((gas_t)g, (las_t)l, 16, 0, 0);
}

// chunk swizzle (involution): LDS slot L <-> global chunk g
static __device__ inline int swz(int L) {
  return (L & ~3) | ((L & 3) ^ ((L >> 3) & 3));
}

static __device__ inline short f2bf(float f) {
  __hip_bfloat16 h = __float2bfloat16(f);
  return *reinterpret_cast<short*>(&h);
}

static __device__ inline float bf2f(short s) {
  unsigned int u = ((unsigned int)(unsigned short)s) << 16;
  return __uint_as_float(u);
}

// block-wide exclusive scan helper (256 threads): returns exclusive prefix, total via ref
static __device__ inline int block_scan_excl(int v, int tid, int* total) {
  __shared__ int warp_sums[4];
  int xinc = v;
  #pragma unroll
  for (int o = 1; o < 64; o <<= 1) {
    int t = __shfl_up(xinc, o);
    if ((tid & 63) >= o) xinc += t;
  }
  int wid = tid >> 6;
  if ((tid & 63) == 63) warp_sums[wid] = xinc;
  __syncthreads();
  int woff = 0;
  #pragma unroll
  for (int w = 0; w < 4; ++w) if (w < wid) woff += warp_sums[w];
  int tot = warp_sums[0] + warp_sums[1] + warp_sums[2] + warp_sums[3];
  if (total) *total = tot;
  return xinc + woff - v;
}

// ---------------- zero an int buffer ----------------
__launch_bounds__(256)
__global__ void k_zero(int* __restrict__ p, int n) {
  int i = blockIdx.x * 256 + threadIdx.x;
  if (i < n) p[i] = 0;
}

// ---------------- x fp32 -> bf16 (row-major unchanged) ----------------
__launch_bounds__(256)
__global__ void k_cvt_x(const float* __restrict__ x, short* __restrict__ xb) {
  int i = blockIdx.x * 256 + threadIdx.x;
  if ((size_t)i * 8 >= (size_t)NN * DIN) return;
  float4 f0 = *(const float4*)(x + (size_t)i * 8);
  float4 f1 = *(const float4*)(x + (size_t)i * 8 + 4);
  short8_t v;
  v[0] = f2bf(f0.x); v[1] = f2bf(f0.y); v[2] = f2bf(f0.z); v[3] = f2bf(f0.w);
  v[4] = f2bf(f1.x); v[5] = f2bf(f1.y); v[6] = f2bf(f1.z); v[7] = f2bf(f1.w);
  *(short8_t*)(xb + (size_t)i * 8) = v;
}

// ---------------- pack fp32 weight [N][K] -> bf16 K-panels P[kb][n][32] ----------------
__launch_bounds__(256)
__global__ void k_pack_w(const float* __restrict__ W, short* __restrict__ P,
                         int N, int K) {
  int id = blockIdx.x * 256 + threadIdx.x;
  int total = N * K;
  if (id >= total) return;
  int kb  = id / (N * 32);
  int rem = id % (N * 32);
  int n   = rem / 32;
  int kk  = rem % 32;
  P[id] = f2bf(W[(size_t)n * K + kb * 32 + kk]);
}

// ---------------- edge weights + in-degree histogram ----------------
__launch_bounds__(256)
__global__ void k_ew_hist(const int* __restrict__ src, const int* __restrict__ dst,
                          const float* __restrict__ pos, float* __restrict__ ew,
                          int* __restrict__ deg) {
  int e = blockIdx.x * 256 + threadIdx.x;
  if (e >= NE) return;
  int s = src[e], d = dst[e];
  ew[e] = 1.0f / (pos[s] - pos[d]);
  atomicAdd(&deg[d], 1);
}

// ---------------- multi-block exclusive scan, phase a: local scan ----------------
__launch_bounds__(256)
__global__ void k_scan_local(const int* __restrict__ deg, int* __restrict__ rowptr,
                             int* __restrict__ bsum) {
  int tid = threadIdx.x;
  int idx = blockIdx.x * 256 + tid;
  int v = (idx < NN) ? deg[idx] : 0;
  int total;
  int ex = block_scan_excl(v, tid, &total);
  if (idx < NN) rowptr[idx] = ex;
  if (tid == 0) bsum[blockIdx.x] = total;
}

// ---------------- phase b: scan the block sums (1 block), write rowptr[NN] ----------
__launch_bounds__(256)
__global__ void k_scan_bsums(int* __restrict__ bsum, int* __restrict__ rowptr) {
  int tid = threadIdx.x;
  int v = (tid < NSCB) ? bsum[tid] : 0;
  int total;
  int ex = block_scan_excl(v, tid, &total);
  if (tid < NSCB) bsum[tid] = ex;
  if (tid == 0) rowptr[NN] = total;
}

// ---------------- phase c: add block offsets ----------------
__launch_bounds__(256)
__global__ void k_scan_add(const int* __restrict__ bsum, int* __restrict__ rowptr) {
  int idx = blockIdx.x * 256 + threadIdx.x;
  if (idx < NN) rowptr[idx] += bsum[blockIdx.x];
}

// ---------------- scatter {src, ew} records into CSR slots ----------------
__launch_bounds__(256)
__global__ void k_scatter(const int* __restrict__ src, const int* __restrict__ dst,
                          const float* __restrict__ ew, const int* __restrict__ rowptr,
                          int* __restrict__ cnt, int2* __restrict__ glist) {
  int e = blockIdx.x * 256 + threadIdx.x;
  if (e >= NE) return;
  int d = dst[e];
  int p = atomicAdd(&cnt[d], 1);
  glist[rowptr[d] + p] = make_int2(src[e], __float_as_int(ew[e]));
}

// ---------------- layer-1 aggregation: wave/node, bf16 x rows (256B) ----------------
__launch_bounds__(256)
__global__ void k_agg1(const int* __restrict__ rowptr, const int2* __restrict__ glist,
                       const short* __restrict__ xb, __hip_bfloat16* __restrict__ agg) {
  int node = blockIdx.x * 4 + (threadIdx.x >> 6);
  int lane = threadIdx.x & 63;
  if (node >= NN) return;
  int beg = rowptr[node], end = rowptr[node + 1];
  float a0 = NEG_INF, a1 = NEG_INF;
  int i = beg;
  for (; i + 2 <= end; i += 2) {
    int2 m0 = glist[i], m1 = glist[i + 1];
    __hip_bfloat162 v0 = *(const __hip_bfloat162*)(xb + (size_t)m0.x * DIN + lane * 2);
    __hip_bfloat162 v1 = *(const __hip_bfloat162*)(xb + (size_t)m1.x * DIN + lane * 2);
    float w0 = __int_as_float(m0.y), w1 = __int_as_float(m1.y);
    float2 f0 = __bfloat1622float2(v0);
    float2 f1 = __bfloat1622float2(v1);
    a0 = fmaxf(a0, fmaxf(f0.x * w0, f1.x * w1));
    a1 = fmaxf(a1, fmaxf(f0.y * w0, f1.y * w1));
  }
  if (i < end) {
    int2 m0 = glist[i];
    __hip_bfloat162 v0 = *(const __hip_bfloat162*)(xb + (size_t)m0.x * DIN + lane * 2);
    float w0 = __int_as_float(m0.y);
    float2 f0 = __bfloat1622float2(v0);
    a0 = fmaxf(a0, f0.x * w0);
    a1 = fmaxf(a1, f0.y * w0);
  }
  if (beg == end) { a0 = 0.0f; a1 = 0.0f; }   // PyG: empty segments -> 0
  *(__hip_bfloat162*)(agg + (size_t)node * DIN + lane * 2) =
      __float22bfloat162_rn(make_float2(a0, a1));
}

// ---------------- layer-2 aggregation: wave/node, 16B/lane rows, 4-deep MLP --------
__launch_bounds__(256)
__global__ void k_agg2(const int* __restrict__ rowptr, const int2* __restrict__ glist,
                       const short* __restrict__ h, __hip_bfloat16* __restrict__ agg) {
  int node = blockIdx.x * 4 + (threadIdx.x >> 6);
  int lane = threadIdx.x & 63;
  if (node >= NN) return;
  int beg = rowptr[node], end = rowptr[node + 1];
  float acc[8];
  #pragma unroll
  for (int j = 0; j < 8; ++j) acc[j] = NEG_INF;
  int i = beg;
  for (; i + 4 <= end; i += 4) {
    int2 m0 = glist[i], m1 = glist[i + 1], m2 = glist[i + 2], m3 = glist[i + 3];
    short8_t v0 = *(const short8_t*)(h + (size_t)m0.x * DH + lane * 8);
    short8_t v1 = *(const short8_t*)(h + (size_t)m1.x * DH + lane * 8);
    short8_t v2 = *(const short8_t*)(h + (size_t)m2.x * DH + lane * 8);
    short8_t v3 = *(const short8_t*)(h + (size_t)m3.x * DH + lane * 8);
    float w0 = __int_as_float(m0.y), w1 = __int_as_float(m1.y);
    float w2 = __int_as_float(m2.y), w3 = __int_as_float(m3.y);
    #pragma unroll
    for (int j = 0; j < 8; ++j) {
      float p01 = fmaxf(bf2f(v0[j]) * w0, bf2f(v1[j]) * w1);
      float p23 = fmaxf(bf2f(v2[j]) * w2, bf2f(v3[j]) * w3);
      acc[j] = fmaxf(acc[j], fmaxf(p01, p23));
    }
  }
  for (; i < end; ++i) {
    int2 m0 = glist[i];
    short8_t v0 = *(const short8_t*)(h + (size_t)m0.x * DH + lane * 8);
    float w0 = __int_as_float(m0.y);
    #pragma unroll
    for (int j = 0; j < 8; ++j)
      acc[j] = fmaxf(acc[j], bf2f(v0[j]) * w0);
  }
  if (beg == end) {
    #pragma unroll
    for (int j = 0; j < 8; ++j) acc[j] = 0.0f;
  }
  short8_t o;
  #pragma unroll
  for (int j = 0; j < 8; ++j) o[j] = f2bf(acc[j]);
  *(short8_t*)((short*)agg + (size_t)node * DH + lane * 8) = o;
}

// ============== MFMA fused dual GEMM + bias + LayerNorm + ReLU -> bf16 ==============
// out[m,:] = relu( LN( A0[m,:]@W0^T + A1[m,:]@W1^T + brel ) * g + b ), bf16.
// A0/A1: [M,K] bf16 row-major. P0/P1: packed bf16 panels P[kb][n(0..511)][32].
// Tile: BM=128 x BN=512 (full row). 512 threads = 8 waves; wave w owns cols w*64..+63,
// all 128 rows (acc[8][4]). Halves weight re-staging vs BM=64.
#define TBM 128

__launch_bounds__(512, 2)
__global__ void k_mfma_ln(const short* __restrict__ A0, const short* __restrict__ P0,
                          const short* __restrict__ A1, const short* __restrict__ P1,
                          const float* __restrict__ brel, const float* __restrict__ gvec,
                          const float* __restrict__ bvec,
                          __hip_bfloat16* __restrict__ out, int K) {
  __shared__ __align__(16) short Bs[DH * 32];    // 32 KB
  __shared__ __align__(16) short As[TBM * 32];   // 8 KB
  __shared__ float2 red[8][TBM];                 // 8 KB

  int tid  = threadIdx.x;
  int wave = tid >> 6;                 // 0..7
  int lane = tid & 63;
  int lhi  = lane >> 4;                // k-chunk selector
  int llo  = lane & 15;                // fragment row (A) / col (B,D)
  int wcol0 = wave * 64;
  int m0 = blockIdx.x * TBM;

  f32x4 acc[8][4];
  #pragma unroll
  for (int ri = 0; ri < 8; ++ri)
    #pragma unroll
    for (int c = 0; c < 4; ++c) acc[ri][c] = (f32x4){0.f, 0.f, 0.f, 0.f};

  for (int pass = 0; pass < 2; ++pass) {
    const short* __restrict__ Aop = pass ? A1 : A0;
    const short* __restrict__ P   = pass ? P1 : P0;
    int nkb = K >> 5;
    for (int kb = 0; kb < nkb; ++kb) {
      // ---- A tile 128x32 = 512 chunks: 1 DMA issue per wave ----
      {
        int L = wave * 64 + lane;
        int g = swz(L);
        int n = g >> 2, c4 = g & 3;
        int gm = m0 + n; if (gm >= NN) gm = NN - 1;
        load_lds16(Aop + (size_t)gm * K + kb * 32 + c4 * 8,
                   (char*)As + wave * 1024);
      }
      // ---- B panel 512x32 = 2048 chunks: 4 DMA issues per wave ----
      const short* __restrict__ panel = P + (size_t)kb * (DH * 32);
      #pragma unroll
      for (int u = 0; u < 4; ++u) {
        int L = wave * 256 + u * 64 + lane;
        int g = swz(L);
        load_lds16(panel + (size_t)g * 8, (char*)Bs + (wave * 256 + u * 64) * 16);
      }
      __syncthreads();                 // drains vmcnt -> DMA complete
      // ---- fragments + 32 MFMAs ----
      short8_t a[8];
      #pragma unroll
      for (int ri = 0; ri < 8; ++ri) {
        int n = ri * 16 + llo;
        int slot = n * 4 + (lhi ^ ((n >> 1) & 3));
        a[ri] = *(const short8_t*)(As + slot * 8);
      }
      #pragma unroll
      for (int c = 0; c < 4; ++c) {
        int n = wcol0 + c * 16 + llo;
        int slot = n * 4 + (lhi ^ ((n >> 1) & 3));
        short8_t bfr = *(const short8_t*)(Bs + slot * 8);
        #pragma unroll
        for (int ri = 0; ri < 8; ++ri)
          acc[ri][c] = __builtin_amdgcn_mfma_f32_16x16x32_bf16(a[ri], bfr, acc[ri][c], 0, 0, 0);
      }
      __syncthreads();
    }
  }

  // ---- epilogue: bias, LN (cross-wave via LDS), scale/shift, relu, bf16 store ----
  float brv[4], gv[4], bev[4];
  #pragma unroll
  for (int c = 0; c < 4; ++c) {
    int col = wcol0 + c * 16 + llo;
    brv[c] = brel[col];
    gv[c]  = gvec[col];
    bev[c] = bvec[col];
  }
  #pragma unroll
  for (int ri = 0; ri < 8; ++ri)
    #pragma unroll
    for (int r = 0; r < 4; ++r) {
      float t = 0.f, tt = 0.f;
      #pragma unroll
      for (int c = 0; c < 4; ++c) {
        float v = acc[ri][c][r] + brv[c];
        t += v; tt += v * v;
      }
      #pragma unroll
      for (int o = 1; o < 16; o <<= 1) {
        t  += __shfl_xor(t, o);
        tt += __shfl_xor(tt, o);
      }
      if (llo == 0) red[wave][ri * 16 + lhi * 4 + r] = make_float2(t, tt);
    }
  __syncthreads();
  if (tid < TBM) {
    float S = 0.f, SS = 0.f;
    #pragma unroll
    for (int w = 0; w < 8; ++w) { float2 p = red[w][tid]; S += p.x; SS += p.y; }
    float mean = S * (1.0f / DH);
    float var  = SS * (1.0f / DH) - mean * mean;
    red[0][tid] = make_float2(mean, rsqrtf(var + 1e-5f));
  }
  __syncthreads();
  #pragma unroll
  for (int ri = 0; ri < 8; ++ri)
    #pragma unroll
    for (int r = 0; r < 4; ++r) {
      int row = ri * 16 + lhi * 4 + r;
      int gm = m0 + row;
      if (gm < NN) {
        float2 mr = red[0][row];
        #pragma unroll
        for (int c = 0; c < 4; ++c) {
          float v = acc[ri][c][r] + brv[c];
          float o = fmaxf((v - mr.x) * mr.y * gv[c] + bev[c], 0.0f);
          out[(size_t)gm * DH + wcol0 + c * 16 + llo] = __float2bfloat16(o);
        }
      }
    }
}

// ============== MFMA classifier GEMM: out = h2 @ Wcls^T + bcls (fp32) ==============
// BM=64 x BN=128, BK=32, 256 threads = 4 waves; wave w owns cols w*32..+31.
#define CBM 64

__launch_bounds__(256)
__global__ void k_mfma_cls(const short* __restrict__ A, const short* __restrict__ P,
                           const float* __restrict__ bias, float* __restrict__ C) {
  __shared__ __align__(16) short Bs[NCLS * 32];  // 8 KB
  __shared__ __align__(16) short As[CBM * 32];   // 4 KB

  int tid  = threadIdx.x;
  int wave = tid >> 6;
  int lane = tid & 63;
  int lhi  = lane >> 4;
  int llo  = lane & 15;
  int wcol0 = wave * 32;
  int m0 = blockIdx.x * CBM;

  f32x4 acc[4][2];
  #pragma unroll
  for (int ri = 0; ri < 4; ++ri)
    #pragma unroll
    for (int c = 0; c < 2; ++c) acc[ri][c] = (f32x4){0.f, 0.f, 0.f, 0.f};

  for (int kb = 0; kb < DH / 32; ++kb) {
    { // A tile 64x32 = 256 chunks: 1 issue per wave
      int L = wave * 64 + lane;
      int g = swz(L);
      int n = g >> 2, c4 = g & 3;
      int gm = m0 + n; if (gm >= NN) gm = NN - 1;
      load_lds16(A + (size_t)gm * DH + kb * 32 + c4 * 8, (char*)As + wave * 1024);
    }
    { // B panel 128x32 = 512 chunks: 2 issues per wave
      const short* __restrict__ panel = P + (size_t)kb * (NCLS * 32);
      #pragma unroll
      for (int u = 0; u < 2; ++u) {
        int L = wave * 128 + u * 64 + lane;
        int g = swz(L);
        load_lds16(panel + (size_t)g * 8, (char*)Bs + (wave * 128 + u * 64) * 16);
      }
    }
    __syncthreads();
    short8_t a[4];
    #pragma unroll
    for (int ri = 0; ri < 4; ++ri) {
      int n = ri * 16 + llo;
      int slot = n * 4 + (lhi ^ ((n >> 1) & 3));
      a[ri] = *(const short8_t*)(As + slot * 8);
    }
    #pragma unroll
    for (int c = 0; c < 2; ++c) {
      int n = wcol0 + c * 16 + llo;
      int slot = n * 4 + (lhi ^ ((n >> 1) & 3));
      short8_t bfr = *(const short8_t*)(Bs + slot * 8);
      #pragma unroll
      for (int ri = 0; ri < 4; ++ri)
        acc[ri][c] = __builtin_amdgcn_mfma_f32_16x16x32_bf16(a[ri], bfr, acc[ri][c], 0, 0, 0);
    }
    __syncthreads();
  }

  #pragma unroll
  for (int c = 0; c < 2; ++c) {
    int col = wcol0 + c * 16 + llo;
    float bc = bias[col];
    #pragma unroll
    for (int ri = 0; ri < 4; ++ri)
      #pragma unroll
      for (int r = 0; r < 4; ++r) {
        int gm = m0 + ri * 16 + lhi * 4 + r;
        if (gm < NN) C[(size_t)gm * NCLS + col] = acc[ri][c][r] + bc;
      }
  }
}

extern "C" void kernel_launch(void* const* d_in, const int* in_sizes, int n_in,
                              void* d_out, int out_size, void* d_ws, size_t ws_size,
                              hipStream_t stream) {
  (void)in_sizes; (void)n_in; (void)out_size; (void)ws_size;
  const float* x      = (const float*)d_in[0];
  const int*   ei     = (const int*)  d_in[1];
  const float* pos    = (const float*)d_in[2];
  const float* Wrel1  = (const float*)d_in[3];
  const float* brel1  = (const float*)d_in[4];
  const float* Wroot1 = (const float*)d_in[5];
  const float* g1     = (const float*)d_in[6];
  const float* b1     = (const float*)d_in[7];
  const float* Wrel2  = (const float*)d_in[8];
  const float* brel2  = (const float*)d_in[9];
  const float* Wroot2 = (const float*)d_in[10];
  const float* g2     = (const float*)d_in[11];
  const float* b2     = (const float*)d_in[12];
  const float* Wcls   = (const float*)d_in[13];
  const float* bcls   = (const float*)d_in[14];
  const int* src = ei;           // edge_index[0]
  const int* dst = ei + NE;      // edge_index[1]
  float* out = (float*)d_out;

  char* ws = (char*)d_ws;
  size_t off = 0;
  auto alloc = [&](size_t bytes) -> void* {
    void* p = ws + off;
    off += (bytes + 255) & ~(size_t)255;
    return p;
  };
  float*           ew     = (float*)          alloc((size_t)NE * 4);
  int*             rowptr = (int*)            alloc((size_t)(NN + 1) * 4);
  int*             cnt    = (int*)            alloc((size_t)NN * 4);
  int*             bsum   = (int*)            alloc((size_t)256 * 4);
  int2*            glist  = (int2*)           alloc((size_t)NE * 8);
  __hip_bfloat16*  agg1   = (__hip_bfloat16*) alloc((size_t)NN * DIN * 2);
  __hip_bfloat16*  h1     = (__hip_bfloat16*) alloc((size_t)NN * DH * 2);
  __hip_bfloat16*  agg2   = (__hip_bfloat16*) alloc((size_t)NN * DH * 2);
  __hip_bfloat16*  h2     = agg2;             // layer-2 GEMM writes in place
  short*           xb     = (short*)agg2;     // bf16 x, overlaps agg2 (see ordering)
  short*           Pr1    = (short*)alloc((size_t)DH * DIN * 2);
  short*           Pq1    = (short*)alloc((size_t)DH * DIN * 2);
  short*           Pr2    = (short*)alloc((size_t)DH * DH * 2);
  short*           Pq2    = (short*)alloc((size_t)DH * DH * 2);
  short*           Pc     = (short*)alloc((size_t)NCLS * DH * 2);

  // ---- weight packing + x conversion ----
  k_pack_w<<<(DH * DIN + 255) / 256, 256, 0, stream>>>(Wrel1,  Pr1, DH,   DIN);
  k_pack_w<<<(DH * DIN + 255) / 256, 256, 0, stream>>>(Wroot1, Pq1, DH,   DIN);
  k_pack_w<<<(DH * DH  + 255) / 256, 256, 0, stream>>>(Wrel2,  Pr2, DH,   DH);
  k_pack_w<<<(DH * DH  + 255) / 256, 256, 0, stream>>>(Wroot2, Pq2, DH,   DH);
  k_pack_w<<<(NCLS * DH + 255) / 256, 256, 0, stream>>>(Wcls,  Pc,  NCLS, DH);
  k_cvt_x<<<(NN * DIN / 8 + 255) / 256, 256, 0, stream>>>(x, xb);

  // ---- CSR build (multi-block scan) ----
  k_zero<<<(NN + 255) / 256, 256, 0, stream>>>(cnt, NN);
  k_ew_hist<<<(NE + 255) / 256, 256, 0, stream>>>(src, dst, pos, ew, cnt);
  k_scan_local<<<NSCB, 256, 0, stream>>>(cnt, rowptr, bsum);
  k_scan_bsums<<<1, 256, 0, stream>>>(bsum, rowptr);
  k_scan_add<<<NSCB, 256, 0, stream>>>(bsum, rowptr);
  k_zero<<<(NN + 255) / 256, 256, 0, stream>>>(cnt, NN);
  k_scatter<<<(NE + 255) / 256, 256, 0, stream>>>(src, dst, ew, rowptr, cnt, glist);

  int gblocks = (NN + TBM - 1) / TBM;
  int ablocks = (NN + 3) / 4;

  // ---- layer 1 (agg1 gathers from bf16 xb) ----
  k_agg1<<<ablocks, 256, 0, stream>>>(rowptr, glist, xb, agg1);
  k_mfma_ln<<<gblocks, 512, 0, stream>>>((const short*)agg1, Pr1,
                                         xb, Pq1,
                                         brel1, g1, b1, h1, DIN);
  // ---- layer 2 (xb dead from here; agg2 reuses its space) ----
  k_agg2<<<ablocks, 256, 0, stream>>>(rowptr, glist, (const short*)h1, agg2);
  k_mfma_ln<<<gblocks, 512, 0, stream>>>((const short*)agg2, Pr2,
                                         (const short*)h1, Pq2,
                                         brel2, g2, b2, h2, DH);
  // ---- classifier ----
  k_mfma_cls<<<(NN + CBM - 1) / CBM, 256, 0, stream>>>((const short*)h2, Pc, bcls, out);
}